// Round 1
// baseline (480.356 us; speedup 1.0000x reference)
//
#include <hip/hip_runtime.h>
#include <hip/hip_bf16.h>

// ---------------------------------------------------------------------------
// SAGE-GCN x3 on MI355X.
// Pipeline per call (all on `stream`, graph-capture safe):
//   1. zero indegree counters
//   2. count in-degrees (int atomics)
//   3. exclusive scan -> CSR offsets (single 1024-thread block, wave scans)
//   4. fill CSR edge_src via atomic cursors
//   5. per layer: Y = X @ W^T (fp32 register-tiled GEMM), then
//      Z = relu?((pull-agg(Y) + 2Y) / (indeg+2) + b)   (one wave per node)
// ---------------------------------------------------------------------------

#define NFEAT 128

// ---------------- CSR build ----------------

__global__ __launch_bounds__(256) void k_zero_int(int* __restrict__ p, int n) {
    int i = blockIdx.x * 256 + threadIdx.x;
    if (i < n) p[i] = 0;
}

__global__ __launch_bounds__(256) void k_count(const int* __restrict__ dst, int* __restrict__ cnt, int ne) {
    int e = blockIdx.x * 256 + threadIdx.x;
    if (e < ne) atomicAdd(&cnt[dst[e]], 1);
}

// single block, 1024 threads: exclusive scan of cnt (in cnt_cursor) -> offs,
// and re-initialize cnt_cursor to the running offsets (fill cursors).
__global__ __launch_bounds__(1024) void k_scan(int* __restrict__ cnt_cursor, int* __restrict__ offs, int n) {
    __shared__ int wtot[16];
    __shared__ int wpre[16];
    __shared__ int sbase;
    int tid  = threadIdx.x;
    int lane = tid & 63;
    int wv   = tid >> 6;
    if (tid == 0) sbase = 0;
    __syncthreads();
    for (int i0 = 0; i0 < n; i0 += 1024) {
        int i = i0 + tid;
        int v = (i < n) ? cnt_cursor[i] : 0;
        int val = v;
        #pragma unroll
        for (int off = 1; off < 64; off <<= 1) {
            int t = __shfl_up(val, off);
            if (lane >= off) val += t;
        }
        if (lane == 63) wtot[wv] = val;
        __syncthreads();
        if (tid == 0) {
            int s = 0;
            #pragma unroll
            for (int w = 0; w < 16; ++w) { wpre[w] = s; s += wtot[w]; }
            wtot[0] = s;  // stash chunk total
        }
        __syncthreads();
        int incl = val + wpre[wv];
        int excl = incl - v;
        int base = sbase;
        if (i < n) { offs[i] = base + excl; cnt_cursor[i] = base + excl; }
        int chunk_total = wtot[0];
        __syncthreads();
        if (tid == 0) sbase = base + chunk_total;
        // barrier at top of next iteration orders the sbase update
    }
    __syncthreads();
    if (tid == 0) offs[n] = sbase;
}

__global__ __launch_bounds__(256) void k_fill(const int* __restrict__ src, const int* __restrict__ dst,
                                              int* __restrict__ cursor, int* __restrict__ esrc, int ne) {
    int e = blockIdx.x * 256 + threadIdx.x;
    if (e < ne) {
        int d = dst[e];
        int p = atomicAdd(&cursor[d], 1);
        esrc[p] = src[e];
    }
}

// ---------------- GEMM: Y[M][N] = X[M][128] @ W[N][128]^T ----------------
// BM=128, BN=64, BK=32, 256 threads, micro-tile 8x4.

__global__ __launch_bounds__(256) void k_gemm_xwt(const float* __restrict__ X, const float* __restrict__ W,
                                                  float* __restrict__ Y, int M, int N) {
    __shared__ float xs[32][132];  // [k][row], padded stride 132 (16B-aligned rows)
    __shared__ float ws[32][68];   // [k][col]
    int tid  = threadIdx.x;
    int brow = blockIdx.x * 128;
    int bcol = blockIdx.y * 64;
    int ri = (tid >> 4) * 8;   // 0..120
    int ci = (tid & 15) * 4;   // 0..60
    float acc[8][4];
    #pragma unroll
    for (int i = 0; i < 8; ++i)
        #pragma unroll
        for (int j = 0; j < 4; ++j) acc[i][j] = 0.f;

    int lr0 = tid >> 3;        // 0..31
    int kk  = (tid & 7) * 4;   // 0..28

    for (int k0 = 0; k0 < 128; k0 += 32) {
        // stage X tile (128 rows x 32 k), transposed into xs
        #pragma unroll
        for (int j = 0; j < 4; ++j) {
            int r  = lr0 + 32 * j;
            int gr = brow + r;
            float4 v = make_float4(0.f, 0.f, 0.f, 0.f);
            if (gr < M) v = *(const float4*)&X[(size_t)gr * 128 + k0 + kk];
            xs[kk + 0][r] = v.x; xs[kk + 1][r] = v.y; xs[kk + 2][r] = v.z; xs[kk + 3][r] = v.w;
        }
        // stage W tile (64 rows x 32 k), transposed into ws
        #pragma unroll
        for (int j = 0; j < 2; ++j) {
            int r = lr0 + 32 * j;
            float4 v = *(const float4*)&W[(size_t)(bcol + r) * 128 + k0 + kk];
            ws[kk + 0][r] = v.x; ws[kk + 1][r] = v.y; ws[kk + 2][r] = v.z; ws[kk + 3][r] = v.w;
        }
        __syncthreads();
        #pragma unroll
        for (int k = 0; k < 32; ++k) {
            float a[8], b[4];
            *(float4*)&a[0] = *(const float4*)&xs[k][ri];
            *(float4*)&a[4] = *(const float4*)&xs[k][ri + 4];
            *(float4*)&b[0] = *(const float4*)&ws[k][ci];
            #pragma unroll
            for (int i = 0; i < 8; ++i)
                #pragma unroll
                for (int j = 0; j < 4; ++j)
                    acc[i][j] = fmaf(a[i], b[j], acc[i][j]);
        }
        __syncthreads();
    }
    #pragma unroll
    for (int i = 0; i < 8; ++i) {
        int gr = brow + ri + i;
        if (gr < M) *(float4*)&Y[(size_t)gr * N + bcol + ci] = *(float4*)&acc[i][0];
    }
}

// ---------------- Aggregation epilogue ----------------
// Z[v] = relu?( (sum_{e in CSR[v]} Y[esrc[e]] + 2*Y[v]) / (indeg+2) + b )
// One wave per node. D=128: float2/lane. D=64: float/lane.

template <int D, bool RELU>
__global__ __launch_bounds__(256) void k_agg(const float* __restrict__ Y, const int* __restrict__ offs,
                                             const int* __restrict__ esrc, const float* __restrict__ bias,
                                             float* __restrict__ Z, int n) {
    int wv   = threadIdx.x >> 6;
    int lane = threadIdx.x & 63;
    int v    = blockIdx.x * 4 + wv;
    if (v >= n) return;
    int start = offs[v];
    int end   = offs[v + 1];
    float scale = 1.0f / (float)(end - start + 2);
    if (D == 128) {
        const float2* Y2 = (const float2*)Y;
        float2 acc = make_float2(0.f, 0.f);
        for (int e = start; e < end; ++e) {
            int s = esrc[e];
            float2 t = Y2[(size_t)s * 64 + lane];
            acc.x += t.x; acc.y += t.y;
        }
        float2 self = Y2[(size_t)v * 64 + lane];
        float2 bb   = ((const float2*)bias)[lane];
        float rx = (acc.x + 2.f * self.x) * scale + bb.x;
        float ry = (acc.y + 2.f * self.y) * scale + bb.y;
        if (RELU) { rx = fmaxf(rx, 0.f); ry = fmaxf(ry, 0.f); }
        ((float2*)Z)[(size_t)v * 64 + lane] = make_float2(rx, ry);
    } else {  // D == 64
        float acc = 0.f;
        for (int e = start; e < end; ++e) {
            int s = esrc[e];
            acc += Y[(size_t)s * 64 + lane];
        }
        float self = Y[(size_t)v * 64 + lane];
        float r = (acc + 2.f * self) * scale + bias[lane];
        if (RELU) r = fmaxf(r, 0.f);
        Z[(size_t)v * 64 + lane] = r;
    }
}

// ---------------- launch ----------------

extern "C" void kernel_launch(void* const* d_in, const int* in_sizes, int n_in,
                              void* d_out, int out_size, void* d_ws, size_t ws_size,
                              hipStream_t stream) {
    const float* in_feat = (const float*)d_in[0];
    const int*   src     = (const int*)d_in[1];
    const int*   dst     = (const int*)d_in[2];
    const float* W0      = (const float*)d_in[3];
    const float* b0      = (const float*)d_in[4];
    const float* W1      = (const float*)d_in[5];
    const float* b1      = (const float*)d_in[6];
    const float* W2      = (const float*)d_in[7];
    const float* b2      = (const float*)d_in[8];
    float* out = (float*)d_out;

    const int n  = in_sizes[0] / NFEAT;   // 50000
    const int ne = in_sizes[1];           // 800000

    // workspace carve (all 16B aligned)
    int* offs   = (int*)d_ws;                        // n+1
    int* cursor = offs + (((n + 1) + 3) & ~3);       // n
    int* esrc   = cursor + ((n + 3) & ~3);           // ne
    float* bufA = (float*)(esrc + ((ne + 3) & ~3));  // n*128
    float* bufB = bufA + (size_t)n * NFEAT;          // n*128

    // --- CSR build ---
    k_zero_int<<<(n + 255) / 256, 256, 0, stream>>>(cursor, n);
    k_count<<<(ne + 255) / 256, 256, 0, stream>>>(dst, cursor, ne);
    k_scan<<<1, 1024, 0, stream>>>(cursor, offs, n);
    k_fill<<<(ne + 255) / 256, 256, 0, stream>>>(src, dst, cursor, esrc, ne);

    const int gm = (n + 127) / 128;  // 391

    // --- layer 0: Y = in_feat @ W0^T ; bufB = relu(agg(Y)) ---
    k_gemm_xwt<<<dim3(gm, 2), 256, 0, stream>>>(in_feat, W0, bufA, n, 128);
    k_agg<128, true><<<(n + 3) / 4, 256, 0, stream>>>(bufA, offs, esrc, b0, bufB, n);

    // --- layer 1 ---
    k_gemm_xwt<<<dim3(gm, 2), 256, 0, stream>>>(bufB, W1, bufA, n, 128);
    k_agg<128, true><<<(n + 3) / 4, 256, 0, stream>>>(bufA, offs, esrc, b1, bufB, n);

    // --- layer 2 (N=64, no relu, straight to d_out) ---
    k_gemm_xwt<<<dim3(gm, 1), 256, 0, stream>>>(bufB, W2, bufA, n, 64);
    k_agg<64, false><<<(n + 3) / 4, 256, 0, stream>>>(bufA, offs, esrc, b2, out, n);

    (void)ws_size; (void)n_in; (void)out_size;
}

// Round 2
// 355.166 us; speedup vs baseline: 1.3525x; 1.3525x over previous
//
#include <hip/hip_runtime.h>
#include <hip/hip_bf16.h>

// ---------------------------------------------------------------------------
// SAGE-GCN x3 on MI355X.
//   1. zero indegree counters
//   2. count in-degrees (int atomics)
//   3. hierarchical exclusive scan -> CSR offsets (3 small kernels, multi-CU)
//   4. fill CSR edge_src via atomic cursors
//   5. per layer: Y = X @ W^T (fp32 register-tiled GEMM), then
//      Z = relu?((pull-agg(Y) + 2Y) / (indeg+2) + b)
//      agg edge loop unrolled 8/4/2/1 for memory-level parallelism
//      (round-1 rocprof: agg latency-bound, VALUBusy 13%, EA 2.5 TB/s)
// ---------------------------------------------------------------------------

#define NFEAT 128

// ---------------- CSR build ----------------

__global__ __launch_bounds__(256) void k_zero_int(int* __restrict__ p, int n) {
    int i = blockIdx.x * 256 + threadIdx.x;
    if (i < n) p[i] = 0;
}

__global__ __launch_bounds__(256) void k_count(const int* __restrict__ dst, int* __restrict__ cnt, int ne) {
    int e = blockIdx.x * 256 + threadIdx.x;
    if (e < ne) atomicAdd(&cnt[dst[e]], 1);
}

// hierarchical scan: partial (per 1024-chunk) -> tops (scan chunk totals) -> add
__global__ __launch_bounds__(1024) void k_scan_part(const int* __restrict__ cnt, int* __restrict__ part,
                                                    int* __restrict__ tots, int n) {
    __shared__ int wtot[16];
    __shared__ int wpre[16];
    int tid  = threadIdx.x;
    int lane = tid & 63;
    int wv   = tid >> 6;
    int i    = blockIdx.x * 1024 + tid;
    int v    = (i < n) ? cnt[i] : 0;
    int val  = v;
    #pragma unroll
    for (int off = 1; off < 64; off <<= 1) {
        int t = __shfl_up(val, off);
        if (lane >= off) val += t;
    }
    if (lane == 63) wtot[wv] = val;
    __syncthreads();
    if (tid == 0) {
        int s = 0;
        #pragma unroll
        for (int w = 0; w < 16; ++w) { wpre[w] = s; s += wtot[w]; }
        tots[blockIdx.x] = s;
    }
    __syncthreads();
    int excl = val - v + wpre[wv];
    if (i < n) part[i] = excl;
}

__global__ __launch_bounds__(1024) void k_scan_tops(int* __restrict__ tots, int* __restrict__ total_out, int nch) {
    __shared__ int wtot[16];
    __shared__ int wpre[16];
    int tid  = threadIdx.x;
    int lane = tid & 63;
    int wv   = tid >> 6;
    int v    = (tid < nch) ? tots[tid] : 0;
    int val  = v;
    #pragma unroll
    for (int off = 1; off < 64; off <<= 1) {
        int t = __shfl_up(val, off);
        if (lane >= off) val += t;
    }
    if (lane == 63) wtot[wv] = val;
    __syncthreads();
    if (tid == 0) {
        int s = 0;
        #pragma unroll
        for (int w = 0; w < 16; ++w) { wpre[w] = s; s += wtot[w]; }
        *total_out = s;
    }
    __syncthreads();
    int excl = val - v + wpre[wv];
    if (tid < nch) tots[tid] = excl;
}

__global__ __launch_bounds__(1024) void k_scan_add(int* __restrict__ offs, int* __restrict__ cursor,
                                                   const int* __restrict__ tots, int n) {
    int i = blockIdx.x * 1024 + threadIdx.x;
    if (i < n) {
        int o = offs[i] + tots[blockIdx.x];
        offs[i]   = o;
        cursor[i] = o;
    }
}

__global__ __launch_bounds__(256) void k_fill(const int* __restrict__ src, const int* __restrict__ dst,
                                              int* __restrict__ cursor, int* __restrict__ esrc, int ne) {
    int e = blockIdx.x * 256 + threadIdx.x;
    if (e < ne) {
        int d = dst[e];
        int p = atomicAdd(&cursor[d], 1);
        esrc[p] = src[e];
    }
}

// ---------------- GEMM: Y[M][N] = X[M][128] @ W[N][128]^T ----------------
// BM=128, BN=64, BK=32, 256 threads, micro-tile 8x4.

__global__ __launch_bounds__(256) void k_gemm_xwt(const float* __restrict__ X, const float* __restrict__ W,
                                                  float* __restrict__ Y, int M, int N) {
    __shared__ float xs[32][132];
    __shared__ float ws[32][68];
    int tid  = threadIdx.x;
    int brow = blockIdx.x * 128;
    int bcol = blockIdx.y * 64;
    int ri = (tid >> 4) * 8;
    int ci = (tid & 15) * 4;
    float acc[8][4];
    #pragma unroll
    for (int i = 0; i < 8; ++i)
        #pragma unroll
        for (int j = 0; j < 4; ++j) acc[i][j] = 0.f;

    int lr0 = tid >> 3;
    int kk  = (tid & 7) * 4;

    for (int k0 = 0; k0 < 128; k0 += 32) {
        #pragma unroll
        for (int j = 0; j < 4; ++j) {
            int r  = lr0 + 32 * j;
            int gr = brow + r;
            float4 v = make_float4(0.f, 0.f, 0.f, 0.f);
            if (gr < M) v = *(const float4*)&X[(size_t)gr * 128 + k0 + kk];
            xs[kk + 0][r] = v.x; xs[kk + 1][r] = v.y; xs[kk + 2][r] = v.z; xs[kk + 3][r] = v.w;
        }
        #pragma unroll
        for (int j = 0; j < 2; ++j) {
            int r = lr0 + 32 * j;
            float4 v = *(const float4*)&W[(size_t)(bcol + r) * 128 + k0 + kk];
            ws[kk + 0][r] = v.x; ws[kk + 1][r] = v.y; ws[kk + 2][r] = v.z; ws[kk + 3][r] = v.w;
        }
        __syncthreads();
        #pragma unroll
        for (int k = 0; k < 32; ++k) {
            float a[8], b[4];
            *(float4*)&a[0] = *(const float4*)&xs[k][ri];
            *(float4*)&a[4] = *(const float4*)&xs[k][ri + 4];
            *(float4*)&b[0] = *(const float4*)&ws[k][ci];
            #pragma unroll
            for (int i = 0; i < 8; ++i)
                #pragma unroll
                for (int j = 0; j < 4; ++j)
                    acc[i][j] = fmaf(a[i], b[j], acc[i][j]);
        }
        __syncthreads();
    }
    #pragma unroll
    for (int i = 0; i < 8; ++i) {
        int gr = brow + ri + i;
        if (gr < M) *(float4*)&Y[(size_t)gr * N + bcol + ci] = *(float4*)&acc[i][0];
    }
}

// ---------------- Aggregation epilogue ----------------
// Z[v] = relu?( (sum_{e in CSR[v]} Y[esrc[e]] + 2*Y[v]) / (indeg+2) + b )
// One wave per node; edge loop unrolled 8/4/2/1 so up to 8 row-gathers are
// in flight per wave (round-1: single-gather-in-flight was latency-bound).

template <int D, bool RELU>
__global__ __launch_bounds__(256) void k_agg(const float* __restrict__ Y, const int* __restrict__ offs,
                                             const int* __restrict__ esrc, const float* __restrict__ bias,
                                             float* __restrict__ Z, int n) {
    int wv   = threadIdx.x >> 6;
    int lane = threadIdx.x & 63;
    int v    = blockIdx.x * 4 + wv;
    if (v >= n) return;
    int start = offs[v];
    int end   = offs[v + 1];
    float scale = 1.0f / (float)(end - start + 2);
    constexpr int VE = D / 64;
    float acc[VE];
    #pragma unroll
    for (int j = 0; j < VE; ++j) acc[j] = 0.f;
    const float2* Y2 = (const float2*)Y;

    int e = start;
    while (e + 8 <= end) {
        int s0 = esrc[e + 0], s1 = esrc[e + 1], s2 = esrc[e + 2], s3 = esrc[e + 3];
        int s4 = esrc[e + 4], s5 = esrc[e + 5], s6 = esrc[e + 6], s7 = esrc[e + 7];
        if (VE == 2) {
            float2 t0 = Y2[(size_t)s0 * 64 + lane], t1 = Y2[(size_t)s1 * 64 + lane];
            float2 t2 = Y2[(size_t)s2 * 64 + lane], t3 = Y2[(size_t)s3 * 64 + lane];
            float2 t4 = Y2[(size_t)s4 * 64 + lane], t5 = Y2[(size_t)s5 * 64 + lane];
            float2 t6 = Y2[(size_t)s6 * 64 + lane], t7 = Y2[(size_t)s7 * 64 + lane];
            acc[0] += t0.x + t1.x + t2.x + t3.x + t4.x + t5.x + t6.x + t7.x;
            acc[1] += t0.y + t1.y + t2.y + t3.y + t4.y + t5.y + t6.y + t7.y;
        } else {
            float t0 = Y[(size_t)s0 * 64 + lane], t1 = Y[(size_t)s1 * 64 + lane];
            float t2 = Y[(size_t)s2 * 64 + lane], t3 = Y[(size_t)s3 * 64 + lane];
            float t4 = Y[(size_t)s4 * 64 + lane], t5 = Y[(size_t)s5 * 64 + lane];
            float t6 = Y[(size_t)s6 * 64 + lane], t7 = Y[(size_t)s7 * 64 + lane];
            acc[0] += t0 + t1 + t2 + t3 + t4 + t5 + t6 + t7;
        }
        e += 8;
    }
    if (e + 4 <= end) {
        int s0 = esrc[e + 0], s1 = esrc[e + 1], s2 = esrc[e + 2], s3 = esrc[e + 3];
        if (VE == 2) {
            float2 t0 = Y2[(size_t)s0 * 64 + lane], t1 = Y2[(size_t)s1 * 64 + lane];
            float2 t2 = Y2[(size_t)s2 * 64 + lane], t3 = Y2[(size_t)s3 * 64 + lane];
            acc[0] += t0.x + t1.x + t2.x + t3.x;
            acc[1] += t0.y + t1.y + t2.y + t3.y;
        } else {
            float t0 = Y[(size_t)s0 * 64 + lane], t1 = Y[(size_t)s1 * 64 + lane];
            float t2 = Y[(size_t)s2 * 64 + lane], t3 = Y[(size_t)s3 * 64 + lane];
            acc[0] += t0 + t1 + t2 + t3;
        }
        e += 4;
    }
    if (e + 2 <= end) {
        int s0 = esrc[e + 0], s1 = esrc[e + 1];
        if (VE == 2) {
            float2 t0 = Y2[(size_t)s0 * 64 + lane], t1 = Y2[(size_t)s1 * 64 + lane];
            acc[0] += t0.x + t1.x;
            acc[1] += t0.y + t1.y;
        } else {
            float t0 = Y[(size_t)s0 * 64 + lane], t1 = Y[(size_t)s1 * 64 + lane];
            acc[0] += t0 + t1;
        }
        e += 2;
    }
    if (e < end) {
        int s0 = esrc[e];
        if (VE == 2) {
            float2 t0 = Y2[(size_t)s0 * 64 + lane];
            acc[0] += t0.x;
            acc[1] += t0.y;
        } else {
            acc[0] += Y[(size_t)s0 * 64 + lane];
        }
    }

    if (VE == 2) {
        float2 self = Y2[(size_t)v * 64 + lane];
        float2 bb   = ((const float2*)bias)[lane];
        float rx = (acc[0] + 2.f * self.x) * scale + bb.x;
        float ry = (acc[1] + 2.f * self.y) * scale + bb.y;
        if (RELU) { rx = fmaxf(rx, 0.f); ry = fmaxf(ry, 0.f); }
        ((float2*)Z)[(size_t)v * 64 + lane] = make_float2(rx, ry);
    } else {
        float self = Y[(size_t)v * 64 + lane];
        float r = (acc[0] + 2.f * self) * scale + bias[lane];
        if (RELU) r = fmaxf(r, 0.f);
        Z[(size_t)v * 64 + lane] = r;
    }
}

// ---------------- launch ----------------

extern "C" void kernel_launch(void* const* d_in, const int* in_sizes, int n_in,
                              void* d_out, int out_size, void* d_ws, size_t ws_size,
                              hipStream_t stream) {
    const float* in_feat = (const float*)d_in[0];
    const int*   src     = (const int*)d_in[1];
    const int*   dst     = (const int*)d_in[2];
    const float* W0      = (const float*)d_in[3];
    const float* b0      = (const float*)d_in[4];
    const float* W1      = (const float*)d_in[5];
    const float* b1      = (const float*)d_in[6];
    const float* W2      = (const float*)d_in[7];
    const float* b2      = (const float*)d_in[8];
    float* out = (float*)d_out;

    const int n  = in_sizes[0] / NFEAT;   // 50000
    const int ne = in_sizes[1];           // 800000
    const int nch = (n + 1023) / 1024;    // 49 (assumed <= 1024)

    // workspace carve (all 16B aligned)
    int* offs   = (int*)d_ws;                         // n+1
    int* cursor = offs + (((n + 1) + 3) & ~3);        // n
    int* tots   = cursor + ((n + 3) & ~3);            // nch (pad to 1024)
    int* esrc   = tots + 1024;                        // ne
    float* bufA = (float*)(esrc + ((ne + 3) & ~3));   // n*128
    float* bufB = bufA + (size_t)n * NFEAT;           // n*128

    // --- CSR build ---
    k_zero_int<<<(n + 255) / 256, 256, 0, stream>>>(cursor, n);
    k_count<<<(ne + 255) / 256, 256, 0, stream>>>(dst, cursor, ne);
    k_scan_part<<<nch, 1024, 0, stream>>>(cursor, offs, tots, n);
    k_scan_tops<<<1, 1024, 0, stream>>>(tots, offs + n, nch);
    k_scan_add<<<nch, 1024, 0, stream>>>(offs, cursor, tots, n);
    k_fill<<<(ne + 255) / 256, 256, 0, stream>>>(src, dst, cursor, esrc, ne);

    const int gm = (n + 127) / 128;  // 391

    // --- layer 0 ---
    k_gemm_xwt<<<dim3(gm, 2), 256, 0, stream>>>(in_feat, W0, bufA, n, 128);
    k_agg<128, true><<<(n + 3) / 4, 256, 0, stream>>>(bufA, offs, esrc, b0, bufB, n);

    // --- layer 1 ---
    k_gemm_xwt<<<dim3(gm, 2), 256, 0, stream>>>(bufB, W1, bufA, n, 128);
    k_agg<128, true><<<(n + 3) / 4, 256, 0, stream>>>(bufA, offs, esrc, b1, bufB, n);

    // --- layer 2 (N=64, no relu, straight to d_out) ---
    k_gemm_xwt<<<dim3(gm, 1), 256, 0, stream>>>(bufB, W2, bufA, n, 64);
    k_agg<64, false><<<(n + 3) / 4, 256, 0, stream>>>(bufA, offs, esrc, b2, out, n);

    (void)ws_size; (void)n_in; (void)out_size;
}

// Round 3
// 270.156 us; speedup vs baseline: 1.7781x; 1.3147x over previous
//
#include <hip/hip_runtime.h>
#include <hip/hip_bf16.h>

// ---------------------------------------------------------------------------
// SAGE-GCN x3 on MI355X.  Round 3: bf16 everywhere on the hot paths.
//   - CSR build (count/scan/fill) as round 2
//   - per layer: Y_bf16 = X @ W^T via MFMA 16x16x32 bf16 (fp32 accum)
//   - agg gathers bf16 rows (256B / 128B), accumulates fp32,
//     writes bf16 (next layer's X) or fp32 (final out)
// Round-2 evidence: agg FETCH == Y_bytes * 8 XCDs (minimal L2 fill) at
// constant fill rate -> halving row bytes should halve agg time.
// ---------------------------------------------------------------------------

#define NFEAT 128

using bf16x8 = __attribute__((ext_vector_type(8))) short;
using f32x4  = __attribute__((ext_vector_type(4))) float;

__device__ __forceinline__ ushort f2bf(float f) {
    unsigned u = __float_as_uint(f);
    u = (u + 0x7fffu + ((u >> 16) & 1u)) >> 16;
    return (ushort)u;
}
__device__ __forceinline__ float bflo(unsigned v) { return __uint_as_float(v << 16); }
__device__ __forceinline__ float bfhi(unsigned v) { return __uint_as_float(v & 0xffff0000u); }

// ---------------- CSR build ----------------

__global__ __launch_bounds__(256) void k_zero_int(int* __restrict__ p, int n) {
    int i = blockIdx.x * 256 + threadIdx.x;
    if (i < n) p[i] = 0;
}

__global__ __launch_bounds__(256) void k_count(const int* __restrict__ dst, int* __restrict__ cnt, int ne) {
    int e = blockIdx.x * 256 + threadIdx.x;
    if (e < ne) atomicAdd(&cnt[dst[e]], 1);
}

__global__ __launch_bounds__(1024) void k_scan_part(const int* __restrict__ cnt, int* __restrict__ part,
                                                    int* __restrict__ tots, int n) {
    __shared__ int wtot[16];
    __shared__ int wpre[16];
    int tid  = threadIdx.x;
    int lane = tid & 63;
    int wv   = tid >> 6;
    int i    = blockIdx.x * 1024 + tid;
    int v    = (i < n) ? cnt[i] : 0;
    int val  = v;
    #pragma unroll
    for (int off = 1; off < 64; off <<= 1) {
        int t = __shfl_up(val, off);
        if (lane >= off) val += t;
    }
    if (lane == 63) wtot[wv] = val;
    __syncthreads();
    if (tid == 0) {
        int s = 0;
        #pragma unroll
        for (int w = 0; w < 16; ++w) { wpre[w] = s; s += wtot[w]; }
        tots[blockIdx.x] = s;
    }
    __syncthreads();
    int excl = val - v + wpre[wv];
    if (i < n) part[i] = excl;
}

__global__ __launch_bounds__(1024) void k_scan_tops(int* __restrict__ tots, int* __restrict__ total_out, int nch) {
    __shared__ int wtot[16];
    __shared__ int wpre[16];
    int tid  = threadIdx.x;
    int lane = tid & 63;
    int wv   = tid >> 6;
    int v    = (tid < nch) ? tots[tid] : 0;
    int val  = v;
    #pragma unroll
    for (int off = 1; off < 64; off <<= 1) {
        int t = __shfl_up(val, off);
        if (lane >= off) val += t;
    }
    if (lane == 63) wtot[wv] = val;
    __syncthreads();
    if (tid == 0) {
        int s = 0;
        #pragma unroll
        for (int w = 0; w < 16; ++w) { wpre[w] = s; s += wtot[w]; }
        *total_out = s;
    }
    __syncthreads();
    int excl = val - v + wpre[wv];
    if (tid < nch) tots[tid] = excl;
}

__global__ __launch_bounds__(1024) void k_scan_add(int* __restrict__ offs, int* __restrict__ cursor,
                                                   const int* __restrict__ tots, int n) {
    int i = blockIdx.x * 1024 + threadIdx.x;
    if (i < n) {
        int o = offs[i] + tots[blockIdx.x];
        offs[i]   = o;
        cursor[i] = o;
    }
}

__global__ __launch_bounds__(256) void k_fill(const int* __restrict__ src, const int* __restrict__ dst,
                                              int* __restrict__ cursor, int* __restrict__ esrc, int ne) {
    int e = blockIdx.x * 256 + threadIdx.x;
    if (e < ne) {
        int d = dst[e];
        int p = atomicAdd(&cursor[d], 1);
        esrc[p] = src[e];
    }
}

// ---------------- cast W0|W1|W2 -> bf16 (concatenated) ----------------

__global__ __launch_bounds__(256) void k_cast3(const float* __restrict__ a, int na,
                                               const float* __restrict__ b, int nb,
                                               const float* __restrict__ c, int nc,
                                               ushort* __restrict__ out) {
    int i = blockIdx.x * 256 + threadIdx.x;
    if (i >= na + nb + nc) return;
    float v = (i < na) ? a[i] : ((i < na + nb) ? b[i - na] : c[i - na - nb]);
    out[i] = f2bf(v);
}

// ---------------- GEMM: Y_bf16[M][N] = X[M][128] @ Wb[N][128]^T ----------------
// MFMA 16x16x32 bf16, fp32 accum. 4 waves/block, each wave: 16 rows x N cols.
// A frag: lane holds X[row = l&15][k = (l>>4)*8 + j]  (16B contiguous load)
// B frag: lane holds W[col = l&15][k = (l>>4)*8 + j]
// C/D:    col = l&15, row = (l>>4)*4 + reg   [m89-verified layout]

template <typename InT, int N>
__global__ __launch_bounds__(256) void k_gemm_mfma(const InT* __restrict__ X, const ushort* __restrict__ Wb,
                                                   ushort* __restrict__ Y, int M) {
    int w    = threadIdx.x >> 6;
    int lane = threadIdx.x & 63;
    int rowf = blockIdx.x * 64 + w * 16 + (lane & 15);  // A-frag row
    int kb   = (lane >> 4) * 8;

    bf16x8 a[4];
    if (rowf < M) {
        #pragma unroll
        for (int ks = 0; ks < 4; ++ks) {
            if constexpr (sizeof(InT) == 2) {
                a[ks] = *(const bf16x8*)((const ushort*)X + (size_t)rowf * 128 + ks * 32 + kb);
            } else {
                const float* xp = (const float*)X + (size_t)rowf * 128 + ks * 32 + kb;
                float4 f0 = *(const float4*)xp;
                float4 f1 = *(const float4*)(xp + 4);
                bf16x8 t;
                t[0] = f2bf(f0.x); t[1] = f2bf(f0.y); t[2] = f2bf(f0.z); t[3] = f2bf(f0.w);
                t[4] = f2bf(f1.x); t[5] = f2bf(f1.y); t[6] = f2bf(f1.z); t[7] = f2bf(f1.w);
                a[ks] = t;
            }
        }
    } else {
        #pragma unroll
        for (int ks = 0; ks < 4; ++ks) {
            bf16x8 z = {0, 0, 0, 0, 0, 0, 0, 0};
            a[ks] = z;
        }
    }

    constexpr int NT = N / 16;
    f32x4 acc[NT];
    #pragma unroll
    for (int nt = 0; nt < NT; ++nt) acc[nt] = (f32x4){0.f, 0.f, 0.f, 0.f};

    #pragma unroll
    for (int nt = 0; nt < NT; ++nt) {
        const ushort* wp = Wb + (size_t)(nt * 16 + (lane & 15)) * 128 + kb;
        #pragma unroll
        for (int ks = 0; ks < 4; ++ks) {
            bf16x8 b = *(const bf16x8*)(wp + ks * 32);
            acc[nt] = __builtin_amdgcn_mfma_f32_16x16x32_bf16(a[ks], b, acc[nt], 0, 0, 0);
        }
    }

    int c  = lane & 15;
    int r0 = blockIdx.x * 64 + w * 16 + (lane >> 4) * 4;
    #pragma unroll
    for (int j = 0; j < 4; ++j) {
        int r = r0 + j;
        if (r < M) {
            #pragma unroll
            for (int nt = 0; nt < NT; ++nt)
                Y[(size_t)r * N + nt * 16 + c] = (ushort)f2bf(acc[nt][j]);
        }
    }
}

// ---------------- Aggregation ----------------
// Z[v] = relu?( (sum_{e} Ybf[esrc[e]] + 2*Ybf[v]) / (indeg+2) + b )
// One wave/node; 8/4/2/1 unroll for MLP.
// D=128: gather uint (2 bf16)/lane, write packed bf16 (uint) -> next X.
// D=64:  gather ushort/lane, write fp32 (final output).

template <bool RELU>
__global__ __launch_bounds__(256) void k_agg128(const unsigned* __restrict__ Y32, const int* __restrict__ offs,
                                                const int* __restrict__ esrc, const float* __restrict__ bias,
                                                unsigned* __restrict__ Z32, int n) {
    int wv   = threadIdx.x >> 6;
    int lane = threadIdx.x & 63;
    int v    = blockIdx.x * 4 + wv;
    if (v >= n) return;
    int start = offs[v];
    int end   = offs[v + 1];
    float scale = 1.0f / (float)(end - start + 2);
    float ax = 0.f, ay = 0.f;

    int e = start;
    while (e + 8 <= end) {
        int s0 = esrc[e + 0], s1 = esrc[e + 1], s2 = esrc[e + 2], s3 = esrc[e + 3];
        int s4 = esrc[e + 4], s5 = esrc[e + 5], s6 = esrc[e + 6], s7 = esrc[e + 7];
        unsigned t0 = Y32[(size_t)s0 * 64 + lane], t1 = Y32[(size_t)s1 * 64 + lane];
        unsigned t2 = Y32[(size_t)s2 * 64 + lane], t3 = Y32[(size_t)s3 * 64 + lane];
        unsigned t4 = Y32[(size_t)s4 * 64 + lane], t5 = Y32[(size_t)s5 * 64 + lane];
        unsigned t6 = Y32[(size_t)s6 * 64 + lane], t7 = Y32[(size_t)s7 * 64 + lane];
        ax += bflo(t0) + bflo(t1) + bflo(t2) + bflo(t3) + bflo(t4) + bflo(t5) + bflo(t6) + bflo(t7);
        ay += bfhi(t0) + bfhi(t1) + bfhi(t2) + bfhi(t3) + bfhi(t4) + bfhi(t5) + bfhi(t6) + bfhi(t7);
        e += 8;
    }
    if (e + 4 <= end) {
        int s0 = esrc[e + 0], s1 = esrc[e + 1], s2 = esrc[e + 2], s3 = esrc[e + 3];
        unsigned t0 = Y32[(size_t)s0 * 64 + lane], t1 = Y32[(size_t)s1 * 64 + lane];
        unsigned t2 = Y32[(size_t)s2 * 64 + lane], t3 = Y32[(size_t)s3 * 64 + lane];
        ax += bflo(t0) + bflo(t1) + bflo(t2) + bflo(t3);
        ay += bfhi(t0) + bfhi(t1) + bfhi(t2) + bfhi(t3);
        e += 4;
    }
    if (e + 2 <= end) {
        int s0 = esrc[e + 0], s1 = esrc[e + 1];
        unsigned t0 = Y32[(size_t)s0 * 64 + lane], t1 = Y32[(size_t)s1 * 64 + lane];
        ax += bflo(t0) + bflo(t1);
        ay += bfhi(t0) + bfhi(t1);
        e += 2;
    }
    if (e < end) {
        unsigned t0 = Y32[(size_t)esrc[e] * 64 + lane];
        ax += bflo(t0);
        ay += bfhi(t0);
    }

    unsigned sf = Y32[(size_t)v * 64 + lane];
    float2 bb = ((const float2*)bias)[lane];
    float rx = (ax + 2.f * bflo(sf)) * scale + bb.x;
    float ry = (ay + 2.f * bfhi(sf)) * scale + bb.y;
    if (RELU) { rx = fmaxf(rx, 0.f); ry = fmaxf(ry, 0.f); }
    Z32[(size_t)v * 64 + lane] = (unsigned)f2bf(rx) | ((unsigned)f2bf(ry) << 16);
}

__global__ __launch_bounds__(256) void k_agg64(const ushort* __restrict__ Y, const int* __restrict__ offs,
                                               const int* __restrict__ esrc, const float* __restrict__ bias,
                                               float* __restrict__ Z, int n) {
    int wv   = threadIdx.x >> 6;
    int lane = threadIdx.x & 63;
    int v    = blockIdx.x * 4 + wv;
    if (v >= n) return;
    int start = offs[v];
    int end   = offs[v + 1];
    float scale = 1.0f / (float)(end - start + 2);
    float acc = 0.f;

    int e = start;
    while (e + 8 <= end) {
        int s0 = esrc[e + 0], s1 = esrc[e + 1], s2 = esrc[e + 2], s3 = esrc[e + 3];
        int s4 = esrc[e + 4], s5 = esrc[e + 5], s6 = esrc[e + 6], s7 = esrc[e + 7];
        float t0 = bflo((unsigned)Y[(size_t)s0 * 64 + lane] << 16 >> 16 | 0u), tdum = 0.f;
        // (simple path: widen each ushort)
        t0 = __uint_as_float((unsigned)Y[(size_t)s0 * 64 + lane] << 16);
        float t1 = __uint_as_float((unsigned)Y[(size_t)s1 * 64 + lane] << 16);
        float t2 = __uint_as_float((unsigned)Y[(size_t)s2 * 64 + lane] << 16);
        float t3 = __uint_as_float((unsigned)Y[(size_t)s3 * 64 + lane] << 16);
        float t4 = __uint_as_float((unsigned)Y[(size_t)s4 * 64 + lane] << 16);
        float t5 = __uint_as_float((unsigned)Y[(size_t)s5 * 64 + lane] << 16);
        float t6 = __uint_as_float((unsigned)Y[(size_t)s6 * 64 + lane] << 16);
        float t7 = __uint_as_float((unsigned)Y[(size_t)s7 * 64 + lane] << 16);
        acc += t0 + t1 + t2 + t3 + t4 + t5 + t6 + t7 + tdum;
        e += 8;
    }
    while (e < end) {
        acc += __uint_as_float((unsigned)Y[(size_t)esrc[e] * 64 + lane] << 16);
        ++e;
    }

    float self = __uint_as_float((unsigned)Y[(size_t)v * 64 + lane] << 16);
    float r = (acc + 2.f * self) * scale + bias[lane];
    Z[(size_t)v * 64 + lane] = r;
}

// ---------------- launch ----------------

extern "C" void kernel_launch(void* const* d_in, const int* in_sizes, int n_in,
                              void* d_out, int out_size, void* d_ws, size_t ws_size,
                              hipStream_t stream) {
    const float* in_feat = (const float*)d_in[0];
    const int*   src     = (const int*)d_in[1];
    const int*   dst     = (const int*)d_in[2];
    const float* W0      = (const float*)d_in[3];
    const float* b0      = (const float*)d_in[4];
    const float* W1      = (const float*)d_in[5];
    const float* b1      = (const float*)d_in[6];
    const float* W2      = (const float*)d_in[7];
    const float* b2      = (const float*)d_in[8];
    float* out = (float*)d_out;

    const int n  = in_sizes[0] / NFEAT;   // 50000
    const int ne = in_sizes[1];           // 800000
    const int nch = (n + 1023) / 1024;

    // workspace carve (16B aligned)
    int* offs     = (int*)d_ws;                        // n+1
    int* cursor   = offs + (((n + 1) + 3) & ~3);       // n
    int* tots     = cursor + ((n + 3) & ~3);           // 1024
    int* esrc     = tots + 1024;                       // ne
    ushort* Wb    = (ushort*)(esrc + ((ne + 7) & ~7)); // 40960 bf16 (W0|W1|W2)
    ushort* Ybuf  = Wb + 40960;                        // n*128 bf16
    ushort* Zbuf  = Ybuf + (size_t)n * NFEAT;          // n*128 bf16

    // --- CSR build ---
    k_zero_int<<<(n + 255) / 256, 256, 0, stream>>>(cursor, n);
    k_count<<<(ne + 255) / 256, 256, 0, stream>>>(dst, cursor, ne);
    k_scan_part<<<nch, 1024, 0, stream>>>(cursor, offs, tots, n);
    k_scan_tops<<<1, 1024, 0, stream>>>(tots, offs + n, nch);
    k_scan_add<<<nch, 1024, 0, stream>>>(offs, cursor, tots, n);
    k_fill<<<(ne + 255) / 256, 256, 0, stream>>>(src, dst, cursor, esrc, ne);

    // --- weights -> bf16 ---
    k_cast3<<<(40960 + 255) / 256, 256, 0, stream>>>(W0, 16384, W1, 16384, W2, 8192, Wb);
    const ushort* Wb0 = Wb;
    const ushort* Wb1 = Wb + 16384;
    const ushort* Wb2 = Wb + 32768;

    const int gg = (n + 63) / 64;  // 782 blocks for GEMM

    // --- layer 0 ---
    k_gemm_mfma<float, 128><<<gg, 256, 0, stream>>>(in_feat, Wb0, Ybuf, n);
    k_agg128<true><<<(n + 3) / 4, 256, 0, stream>>>((const unsigned*)Ybuf, offs, esrc, b0, (unsigned*)Zbuf, n);

    // --- layer 1 ---
    k_gemm_mfma<ushort, 128><<<gg, 256, 0, stream>>>(Zbuf, Wb1, Ybuf, n);
    k_agg128<true><<<(n + 3) / 4, 256, 0, stream>>>((const unsigned*)Ybuf, offs, esrc, b1, (unsigned*)Zbuf, n);

    // --- layer 2 (N=64, no relu, fp32 out) ---
    k_gemm_mfma<ushort, 64><<<gg, 256, 0, stream>>>(Zbuf, Wb2, Ybuf, n);
    k_agg64<<<(n + 3) / 4, 256, 0, stream>>>(Ybuf, offs, esrc, b2, out, n);

    (void)ws_size; (void)n_in; (void)out_size;
}

// Round 4
// 257.774 us; speedup vs baseline: 1.8635x; 1.0480x over previous
//
#include <hip/hip_runtime.h>
#include <hip/hip_bf16.h>

// ---------------------------------------------------------------------------
// SAGE-GCN x3 on MI355X.  Round 4.
//   CSR build: bucketed 2-pass (bin -> count -> scan -> scatter) to kill the
//     16x cross-XCD write amplification rocprof showed on the old k_fill
//     (WRITE_SIZE 52MB for 3.2MB logical; 800k partial 64B lines).
//   Agg: feature-half split keyed to blockIdx parity (XCD round-robin
//     heuristic) -> each XCD fills only half of Y into its L2.
//   GEMM: MFMA 16x16x32 bf16 as round 3.
// Assumes n <= 65536 (src packed in 16 bits) -- true here (n=50000).
// ---------------------------------------------------------------------------

#define NFEAT 128
#define BKT_CAP 12288   // per-bucket pair capacity (avg ~8163 @ n=50000)

using bf16x8 = __attribute__((ext_vector_type(8))) short;
using f32x4  = __attribute__((ext_vector_type(4))) float;

__device__ __forceinline__ ushort f2bf(float f) {
    unsigned u = __float_as_uint(f);
    u = (u + 0x7fffu + ((u >> 16) & 1u)) >> 16;
    return (ushort)u;
}
__device__ __forceinline__ float bflo(unsigned v) { return __uint_as_float(v << 16); }
__device__ __forceinline__ float bfhi(unsigned v) { return __uint_as_float(v & 0xffff0000u); }

// ---------------- CSR build ----------------

__global__ __launch_bounds__(128) void k_zero128(int* __restrict__ p) {
    p[threadIdx.x] = 0;
}

// Pass A: bin edges into 512-node buckets; block-aggregated cursor alloc.
__global__ __launch_bounds__(256) void k_bin(const int* __restrict__ src, const int* __restrict__ dst,
                                             int* __restrict__ gcur, unsigned* __restrict__ pairs, int ne) {
    __shared__ int lcnt[128];
    __shared__ int lbase[128];
    int tid = threadIdx.x;
    if (tid < 128) lcnt[tid] = 0;
    __syncthreads();
    int e0 = blockIdx.x * 4096;
    int myrank[16];
    int mybkt[16];
    unsigned mypair[16];
    #pragma unroll
    for (int i = 0; i < 16; ++i) {
        int e = e0 + tid + i * 256;
        if (e < ne) {
            int s = src[e], d = dst[e];
            int b = d >> 9;
            mybkt[i]  = b;
            mypair[i] = (unsigned)(s & 0xffff) | ((unsigned)(d & 511) << 16);
            myrank[i] = atomicAdd(&lcnt[b], 1);
        } else mybkt[i] = -1;
    }
    __syncthreads();
    if (tid < 128) lbase[tid] = lcnt[tid] ? atomicAdd(&gcur[tid], lcnt[tid]) : 0;
    __syncthreads();
    #pragma unroll
    for (int i = 0; i < 16; ++i) {
        if (mybkt[i] >= 0) {
            int pos = lbase[mybkt[i]] + myrank[i];
            if (pos < BKT_CAP) pairs[(size_t)mybkt[i] * BKT_CAP + pos] = mypair[i];
        }
    }
}

// Pass B1: per-bucket per-node counts, written coalesced.
__global__ __launch_bounds__(256) void k_cnt(const unsigned* __restrict__ pairs, const int* __restrict__ gcur,
                                             int* __restrict__ cnt, int n) {
    __shared__ int lcnt[512];
    int b = blockIdx.x, tid = threadIdx.x;
    for (int i = tid; i < 512; i += 256) lcnt[i] = 0;
    __syncthreads();
    int m = gcur[b];
    if (m > BKT_CAP) m = BKT_CAP;
    const unsigned* p = pairs + (size_t)b * BKT_CAP;
    for (int i = tid; i < m; i += 256) atomicAdd(&lcnt[p[i] >> 16], 1);
    __syncthreads();
    int base = b * 512;
    for (int i = tid; i < 512; i += 256) {
        int node = base + i;
        if (node < n) cnt[node] = lcnt[i];
    }
}

// hierarchical scan: cnt -> offs
__global__ __launch_bounds__(1024) void k_scan_part(const int* __restrict__ cnt, int* __restrict__ part,
                                                    int* __restrict__ tots, int n) {
    __shared__ int wtot[16];
    __shared__ int wpre[16];
    int tid  = threadIdx.x;
    int lane = tid & 63;
    int wv   = tid >> 6;
    int i    = blockIdx.x * 1024 + tid;
    int v    = (i < n) ? cnt[i] : 0;
    int val  = v;
    #pragma unroll
    for (int off = 1; off < 64; off <<= 1) {
        int t = __shfl_up(val, off);
        if (lane >= off) val += t;
    }
    if (lane == 63) wtot[wv] = val;
    __syncthreads();
    if (tid == 0) {
        int s = 0;
        #pragma unroll
        for (int w = 0; w < 16; ++w) { wpre[w] = s; s += wtot[w]; }
        tots[blockIdx.x] = s;
    }
    __syncthreads();
    int excl = val - v + wpre[wv];
    if (i < n) part[i] = excl;
}

__global__ __launch_bounds__(1024) void k_scan_tops(int* __restrict__ tots, int* __restrict__ total_out, int nch) {
    __shared__ int wtot[16];
    __shared__ int wpre[16];
    int tid  = threadIdx.x;
    int lane = tid & 63;
    int wv   = tid >> 6;
    int v    = (tid < nch) ? tots[tid] : 0;
    int val  = v;
    #pragma unroll
    for (int off = 1; off < 64; off <<= 1) {
        int t = __shfl_up(val, off);
        if (lane >= off) val += t;
    }
    if (lane == 63) wtot[wv] = val;
    __syncthreads();
    if (tid == 0) {
        int s = 0;
        #pragma unroll
        for (int w = 0; w < 16; ++w) { wpre[w] = s; s += wtot[w]; }
        *total_out = s;
    }
    __syncthreads();
    int excl = val - v + wpre[wv];
    if (tid < nch) tots[tid] = excl;
}

__global__ __launch_bounds__(1024) void k_scan_add(int* __restrict__ offs, const int* __restrict__ tots, int n) {
    int i = blockIdx.x * 1024 + threadIdx.x;
    if (i < n) offs[i] += tots[blockIdx.x];
}

// Pass B2: per-bucket scatter into esrc (one block per bucket -> one XCD
// owns each 512-node esrc window; full lines, no cross-XCD sharing).
__global__ __launch_bounds__(256) void k_scatter(const unsigned* __restrict__ pairs, const int* __restrict__ gcur,
                                                 const int* __restrict__ offs, int* __restrict__ esrc, int n) {
    __shared__ int lcur[512];
    __shared__ int loffs[512];
    int b = blockIdx.x, tid = threadIdx.x;
    int base = b * 512;
    for (int i = tid; i < 512; i += 256) {
        lcur[i] = 0;
        int node = base + i;
        loffs[i] = (node < n) ? offs[node] : 0;
    }
    __syncthreads();
    int m = gcur[b];
    if (m > BKT_CAP) m = BKT_CAP;
    const unsigned* p = pairs + (size_t)b * BKT_CAP;
    for (int i = tid; i < m; i += 256) {
        unsigned pr = p[i];
        int dlow = pr >> 16;
        int r = atomicAdd(&lcur[dlow], 1);
        esrc[loffs[dlow] + r] = (int)(pr & 0xffffu);
    }
}

// ---------------- cast W0|W1|W2 -> bf16 ----------------

__global__ __launch_bounds__(256) void k_cast3(const float* __restrict__ a, int na,
                                               const float* __restrict__ b, int nb,
                                               const float* __restrict__ c, int nc,
                                               ushort* __restrict__ out) {
    int i = blockIdx.x * 256 + threadIdx.x;
    if (i >= na + nb + nc) return;
    float v = (i < na) ? a[i] : ((i < na + nb) ? b[i - na] : c[i - na - nb]);
    out[i] = f2bf(v);
}

// ---------------- GEMM: Y_bf16[M][N] = X[M][128] @ Wb[N][128]^T ----------------

template <typename InT, int N>
__global__ __launch_bounds__(256) void k_gemm_mfma(const InT* __restrict__ X, const ushort* __restrict__ Wb,
                                                   ushort* __restrict__ Y, int M) {
    int w    = threadIdx.x >> 6;
    int lane = threadIdx.x & 63;
    int rowf = blockIdx.x * 64 + w * 16 + (lane & 15);
    int kb   = (lane >> 4) * 8;

    bf16x8 a[4];
    if (rowf < M) {
        #pragma unroll
        for (int ks = 0; ks < 4; ++ks) {
            if constexpr (sizeof(InT) == 2) {
                a[ks] = *(const bf16x8*)((const ushort*)X + (size_t)rowf * 128 + ks * 32 + kb);
            } else {
                const float* xp = (const float*)X + (size_t)rowf * 128 + ks * 32 + kb;
                float4 f0 = *(const float4*)xp;
                float4 f1 = *(const float4*)(xp + 4);
                bf16x8 t;
                t[0] = f2bf(f0.x); t[1] = f2bf(f0.y); t[2] = f2bf(f0.z); t[3] = f2bf(f0.w);
                t[4] = f2bf(f1.x); t[5] = f2bf(f1.y); t[6] = f2bf(f1.z); t[7] = f2bf(f1.w);
                a[ks] = t;
            }
        }
    } else {
        #pragma unroll
        for (int ks = 0; ks < 4; ++ks) {
            bf16x8 z = {0, 0, 0, 0, 0, 0, 0, 0};
            a[ks] = z;
        }
    }

    constexpr int NT = N / 16;
    f32x4 acc[NT];
    #pragma unroll
    for (int nt = 0; nt < NT; ++nt) acc[nt] = (f32x4){0.f, 0.f, 0.f, 0.f};

    #pragma unroll
    for (int nt = 0; nt < NT; ++nt) {
        const ushort* wp = Wb + (size_t)(nt * 16 + (lane & 15)) * 128 + kb;
        #pragma unroll
        for (int ks = 0; ks < 4; ++ks) {
            bf16x8 b = *(const bf16x8*)(wp + ks * 32);
            acc[nt] = __builtin_amdgcn_mfma_f32_16x16x32_bf16(a[ks], b, acc[nt], 0, 0, 0);
        }
    }

    int c  = lane & 15;
    int r0 = blockIdx.x * 64 + w * 16 + (lane >> 4) * 4;
    #pragma unroll
    for (int j = 0; j < 4; ++j) {
        int r = r0 + j;
        if (r < M) {
            #pragma unroll
            for (int nt = 0; nt < NT; ++nt)
                Y[(size_t)r * N + nt * 16 + c] = (ushort)f2bf(acc[nt][j]);
        }
    }
}

// ---------------- Aggregation ----------------
// Feature-half split: hsel = blockIdx&1 (XCD round-robin parity heuristic).
// Wave = 2 nodes x 32 lanes; each 32-lane group reads a 128B half-row.

template <bool RELU>
__global__ __launch_bounds__(256) void k_agg128(const unsigned* __restrict__ Y32, const int* __restrict__ offs,
                                                const int* __restrict__ esrc, const float* __restrict__ bias,
                                                unsigned* __restrict__ Z32, int n) {
    int w    = threadIdx.x >> 6;
    int lane = threadIdx.x & 63;
    int half = lane >> 5;
    int l32  = lane & 31;
    int hsel = blockIdx.x & 1;
    int v    = (blockIdx.x >> 1) * 8 + w * 2 + half;
    if (v >= n) return;
    const unsigned* Yc = Y32 + hsel * 32 + l32;
    int start = offs[v];
    int end   = offs[v + 1];
    float scale = 1.0f / (float)(end - start + 2);
    float ax = 0.f, ay = 0.f;

    int e = start;
    while (e + 8 <= end) {
        int s0 = esrc[e + 0], s1 = esrc[e + 1], s2 = esrc[e + 2], s3 = esrc[e + 3];
        int s4 = esrc[e + 4], s5 = esrc[e + 5], s6 = esrc[e + 6], s7 = esrc[e + 7];
        unsigned t0 = Yc[(size_t)s0 * 64], t1 = Yc[(size_t)s1 * 64];
        unsigned t2 = Yc[(size_t)s2 * 64], t3 = Yc[(size_t)s3 * 64];
        unsigned t4 = Yc[(size_t)s4 * 64], t5 = Yc[(size_t)s5 * 64];
        unsigned t6 = Yc[(size_t)s6 * 64], t7 = Yc[(size_t)s7 * 64];
        ax += bflo(t0) + bflo(t1) + bflo(t2) + bflo(t3) + bflo(t4) + bflo(t5) + bflo(t6) + bflo(t7);
        ay += bfhi(t0) + bfhi(t1) + bfhi(t2) + bfhi(t3) + bfhi(t4) + bfhi(t5) + bfhi(t6) + bfhi(t7);
        e += 8;
    }
    if (e + 4 <= end) {
        int s0 = esrc[e + 0], s1 = esrc[e + 1], s2 = esrc[e + 2], s3 = esrc[e + 3];
        unsigned t0 = Yc[(size_t)s0 * 64], t1 = Yc[(size_t)s1 * 64];
        unsigned t2 = Yc[(size_t)s2 * 64], t3 = Yc[(size_t)s3 * 64];
        ax += bflo(t0) + bflo(t1) + bflo(t2) + bflo(t3);
        ay += bfhi(t0) + bfhi(t1) + bfhi(t2) + bfhi(t3);
        e += 4;
    }
    if (e + 2 <= end) {
        int s0 = esrc[e + 0], s1 = esrc[e + 1];
        unsigned t0 = Yc[(size_t)s0 * 64], t1 = Yc[(size_t)s1 * 64];
        ax += bflo(t0) + bflo(t1);
        ay += bfhi(t0) + bfhi(t1);
        e += 2;
    }
    if (e < end) {
        unsigned t0 = Yc[(size_t)esrc[e] * 64];
        ax += bflo(t0);
        ay += bfhi(t0);
    }

    unsigned sf = Yc[(size_t)v * 64];
    float2 bb = ((const float2*)bias)[hsel * 32 + l32];
    float rx = (ax + 2.f * bflo(sf)) * scale + bb.x;
    float ry = (ay + 2.f * bfhi(sf)) * scale + bb.y;
    if (RELU) { rx = fmaxf(rx, 0.f); ry = fmaxf(ry, 0.f); }
    Z32[(size_t)v * 64 + hsel * 32 + l32] = (unsigned)f2bf(rx) | ((unsigned)f2bf(ry) << 16);
}

__global__ __launch_bounds__(256) void k_agg64(const ushort* __restrict__ Y, const int* __restrict__ offs,
                                               const int* __restrict__ esrc, const float* __restrict__ bias,
                                               float* __restrict__ Z, int n) {
    int w    = threadIdx.x >> 6;
    int lane = threadIdx.x & 63;
    int half = lane >> 5;
    int l32  = lane & 31;
    int hsel = blockIdx.x & 1;
    int f    = hsel * 32 + l32;
    int v    = (blockIdx.x >> 1) * 8 + w * 2 + half;
    if (v >= n) return;
    const ushort* Yc = Y + f;
    int start = offs[v];
    int end   = offs[v + 1];
    float scale = 1.0f / (float)(end - start + 2);
    float acc = 0.f;

    int e = start;
    while (e + 8 <= end) {
        int s0 = esrc[e + 0], s1 = esrc[e + 1], s2 = esrc[e + 2], s3 = esrc[e + 3];
        int s4 = esrc[e + 4], s5 = esrc[e + 5], s6 = esrc[e + 6], s7 = esrc[e + 7];
        float t0 = __uint_as_float((unsigned)Yc[(size_t)s0 * 64] << 16);
        float t1 = __uint_as_float((unsigned)Yc[(size_t)s1 * 64] << 16);
        float t2 = __uint_as_float((unsigned)Yc[(size_t)s2 * 64] << 16);
        float t3 = __uint_as_float((unsigned)Yc[(size_t)s3 * 64] << 16);
        float t4 = __uint_as_float((unsigned)Yc[(size_t)s4 * 64] << 16);
        float t5 = __uint_as_float((unsigned)Yc[(size_t)s5 * 64] << 16);
        float t6 = __uint_as_float((unsigned)Yc[(size_t)s6 * 64] << 16);
        float t7 = __uint_as_float((unsigned)Yc[(size_t)s7 * 64] << 16);
        acc += t0 + t1 + t2 + t3 + t4 + t5 + t6 + t7;
        e += 8;
    }
    while (e < end) {
        acc += __uint_as_float((unsigned)Yc[(size_t)esrc[e] * 64] << 16);
        ++e;
    }

    float self = __uint_as_float((unsigned)Yc[(size_t)v * 64] << 16);
    float r = (acc + 2.f * self) * scale + bias[f];
    Z[(size_t)v * 64 + f] = r;
}

// ---------------- launch ----------------

extern "C" void kernel_launch(void* const* d_in, const int* in_sizes, int n_in,
                              void* d_out, int out_size, void* d_ws, size_t ws_size,
                              hipStream_t stream) {
    const float* in_feat = (const float*)d_in[0];
    const int*   src     = (const int*)d_in[1];
    const int*   dst     = (const int*)d_in[2];
    const float* W0      = (const float*)d_in[3];
    const float* b0      = (const float*)d_in[4];
    const float* W1      = (const float*)d_in[5];
    const float* b1      = (const float*)d_in[6];
    const float* W2      = (const float*)d_in[7];
    const float* b2      = (const float*)d_in[8];
    float* out = (float*)d_out;

    const int n  = in_sizes[0] / NFEAT;   // 50000 (<= 65536 assumed)
    const int ne = in_sizes[1];           // 800000
    const int nch = (n + 1023) / 1024;
    const int NB  = (n + 511) >> 9;       // 98 buckets

    // workspace carve (16B aligned)
    int* offs       = (int*)d_ws;                          // n+1
    int* tots       = offs + (((n + 1) + 3) & ~3);         // 1024
    int* gcur       = tots + 1024;                         // 128
    int* cnt        = gcur + 128;                          // n
    unsigned* pairs = (unsigned*)(cnt + ((n + 3) & ~3));   // 128*BKT_CAP
    int* esrc       = (int*)(pairs + (size_t)128 * BKT_CAP);
    ushort* Wb      = (ushort*)(esrc + ((ne + 7) & ~7));   // 40960
    ushort* Ybuf    = Wb + 40960;                          // n*128
    ushort* Zbuf    = Ybuf + (size_t)n * NFEAT;            // n*128

    // --- CSR build ---
    k_zero128<<<1, 128, 0, stream>>>(gcur);
    k_bin<<<(ne + 4095) / 4096, 256, 0, stream>>>(src, dst, gcur, pairs, ne);
    k_cnt<<<NB, 256, 0, stream>>>(pairs, gcur, cnt, n);
    k_scan_part<<<nch, 1024, 0, stream>>>(cnt, offs, tots, n);
    k_scan_tops<<<1, 1024, 0, stream>>>(tots, offs + n, nch);
    k_scan_add<<<nch, 1024, 0, stream>>>(offs, tots, n);
    k_scatter<<<NB, 256, 0, stream>>>(pairs, gcur, offs, esrc, n);

    // --- weights -> bf16 ---
    k_cast3<<<(40960 + 255) / 256, 256, 0, stream>>>(W0, 16384, W1, 16384, W2, 8192, Wb);
    const ushort* Wb0 = Wb;
    const ushort* Wb1 = Wb + 16384;
    const ushort* Wb2 = Wb + 32768;

    const int gg = (n + 63) / 64;                 // GEMM blocks
    const int ga = 2 * ((n + 7) / 8);             // agg blocks (feature-split x2)

    // --- layer 0 ---
    k_gemm_mfma<float, 128><<<gg, 256, 0, stream>>>(in_feat, Wb0, Ybuf, n);
    k_agg128<true><<<ga, 256, 0, stream>>>((const unsigned*)Ybuf, offs, esrc, b0, (unsigned*)Zbuf, n);

    // --- layer 1 ---
    k_gemm_mfma<ushort, 128><<<gg, 256, 0, stream>>>(Zbuf, Wb1, Ybuf, n);
    k_agg128<true><<<ga, 256, 0, stream>>>((const unsigned*)Ybuf, offs, esrc, b1, (unsigned*)Zbuf, n);

    // --- layer 2 (N=64, no relu, fp32 out) ---
    k_gemm_mfma<ushort, 64><<<gg, 256, 0, stream>>>(Zbuf, Wb2, Ybuf, n);
    k_agg64<<<ga, 256, 0, stream>>>(Ybuf, offs, esrc, b2, out, n);

    (void)ws_size; (void)n_in; (void)out_size;
}